// Round 6
// baseline (3682.870 us; speedup 1.0000x reference)
//
#include <hip/hip_runtime.h>
#include <hip/hip_fp16.h>

#define TPB 256

typedef _Float16 h2v __attribute__((ext_vector_type(2)));

__device__ __forceinline__ float dot2f(unsigned int a, unsigned int b, float c) {
#if __has_builtin(__builtin_amdgcn_fdot2)
    return __builtin_amdgcn_fdot2(__builtin_bit_cast(h2v, a), __builtin_bit_cast(h2v, b), c, false);
#else
    float2 af = __half22float2(__builtin_bit_cast(__half2, a));
    float2 bf = __half22float2(__builtin_bit_cast(__half2, b));
    return fmaf(af.y, bf.y, fmaf(af.x, bf.x, c));
#endif
}

__device__ __forceinline__ unsigned int pack2(float a, float b) {
    unsigned int lo = (unsigned int)__half_as_ushort(__float2half_rn(a));
    unsigned int hi = (unsigned int)__half_as_ushort(__float2half_rn(b));
    return lo | (hi << 16);
}

__device__ __forceinline__ float softplus_f(float x) {
    return fmaxf(x, 0.f) + __logf(1.f + __expf(-fabsf(x)));
}
__device__ __forceinline__ float tanh_f(float x) {
    float e = __expf(2.f * x);
    return 1.f - 2.f / (e + 1.f);
}
__device__ __forceinline__ float sigmoid_f(float x) {
    return 1.f / (1.f + __expf(-x));
}

// DPP add-reduce: 0xB1 = quad_perm xor1, 0x4E = quad_perm xor2 (both self-inverse)
template <int CTRL>
__device__ __forceinline__ float dpp_add(float x) {
    int m = __builtin_amdgcn_update_dpp(0, __builtin_bit_cast(int, x), CTRL, 0xF, 0xF, true);
    return x + __builtin_bit_cast(float, m);
}

__device__ __forceinline__ float dot32(const float* w, const float* base) {
    float s0 = 0.f, s1 = 0.f, s2 = 0.f, s3 = 0.f;
#pragma unroll
    for (int q = 0; q < 8; ++q) {
        float4 v = *reinterpret_cast<const float4*>(base + 4 * q);
        s0 = fmaf(w[4 * q + 0], v.x, s0);
        s1 = fmaf(w[4 * q + 1], v.y, s1);
        s2 = fmaf(w[4 * q + 2], v.z, s2);
        s3 = fmaf(w[4 * q + 3], v.w, s3);
    }
    return (s0 + s1) + (s2 + s3);
}

__device__ __forceinline__ unsigned int u4c(uint4 v, int i) {
    return i == 0 ? v.x : (i == 1 ? v.y : (i == 2 ? v.z : v.w));
}

__global__ __launch_bounds__(TPB, 1) void ncde_kernel(
    const float* __restrict__ timestamps, const float* __restrict__ obs,
    const float* __restrict__ coef_d, const float* __restrict__ coef_c,
    const float* __restrict__ coef_b, const float* __restrict__ coef_a,
    const float* __restrict__ gru_wih, const float* __restrict__ gru_whh,
    const float* __restrict__ gru_bih, const float* __restrict__ gru_bhh,
    const float* __restrict__ gru_lin_w,
    const float* __restrict__ ie_w0, const float* __restrict__ ie_b0,
    const float* __restrict__ ie_wh, const float* __restrict__ ie_bh,
    const float* __restrict__ ie_wout, const float* __restrict__ ie_bout,
    const float* __restrict__ vf_w0, const float* __restrict__ vf_b0,
    const float* __restrict__ vf_wh, const float* __restrict__ vf_bh,
    const float* __restrict__ vf_wout, const float* __restrict__ vf_bout,
    const float* __restrict__ dec_w0, const float* __restrict__ dec_b0,
    const float* __restrict__ dec_wh, const float* __restrict__ dec_bh,
    const float* __restrict__ dec_wout, const float* __restrict__ dec_bout,
    float* __restrict__ out)
{
    const int b = blockIdx.x;
    const int tid = threadIdx.x;

    __shared__ __align__(16) float s_ysall[128][64];   // all y states (for decoder)
    __shared__ __align__(16) float s_whh[192 * 65];    // GRU Whh, padded rows
    __shared__ __align__(16) float s_wih[192 * 9];     // GRU Wih, padded
    __shared__ __align__(16) float s_obs[24 * 8];
    __shared__ float s_gi[192];
    __shared__ float s_gh[192];
    __shared__ __align__(16) float s_y[64];            // ODE state (also GRU hidden early)
    __shared__ __align__(16) __half s_h1h[128];
    __shared__ __align__(16) __half s_h2h[128];
    __shared__ __align__(16) float s_k[6][64];
    __shared__ float s_bi[16], s_ci[16], s_di[16];
    __shared__ __align__(16) float s_v48[48];
    __shared__ float s_m1[128], s_m2[128];

    // ---- stage GRU weights into LDS ----
    for (int idx = tid; idx < 192 * 64; idx += TPB)
        s_whh[(idx >> 6) * 65 + (idx & 63)] = gru_whh[idx];
    for (int idx = tid; idx < 192 * 8; idx += TPB)
        s_wih[(idx >> 3) * 9 + (idx & 7)] = gru_wih[idx];
    if (tid < 24 * 8) s_obs[tid] = obs[(size_t)b * 192 + tid];
    const float bih_r = (tid < 192) ? gru_bih[tid] : 0.f;
    const float bhh_r = (tid < 192) ? gru_bhh[tid] : 0.f;
    if (tid < 64) s_y[tid] = 0.f;   // GRU hidden init
    __syncthreads();

    // ---- GRU over 24 steps ----
    for (int step = 0; step < 24; ++step) {
        if (tid < 192) {
            float gi = bih_r;
            const float* wr = &s_wih[tid * 9];
            const float* xr = &s_obs[step * 8];
#pragma unroll
            for (int j = 0; j < 8; ++j) gi = fmaf(wr[j], xr[j], gi);
            float g0 = bhh_r, g1 = 0.f, g2 = 0.f, g3 = 0.f;
            const float* hr = &s_whh[tid * 65];
#pragma unroll 4
            for (int j = 0; j < 64; j += 4) {
                g0 = fmaf(hr[j + 0], s_y[j + 0], g0);
                g1 = fmaf(hr[j + 1], s_y[j + 1], g1);
                g2 = fmaf(hr[j + 2], s_y[j + 2], g2);
                g3 = fmaf(hr[j + 3], s_y[j + 3], g3);
            }
            s_gi[tid] = gi;
            s_gh[tid] = (g0 + g1) + (g2 + g3);
        }
        __syncthreads();
        if (tid < 64) {
            float rg = sigmoid_f(s_gi[tid] + s_gh[tid]);
            float zg = sigmoid_f(s_gi[64 + tid] + s_gh[64 + tid]);
            float ng = tanh_f(s_gi[128 + tid] + rg * s_gh[128 + tid]);
            s_y[tid] = (1.f - zg) * ng + zg * s_y[tid];
        }
        __syncthreads();
    }

    // ---- enc = gru_lin_w @ hT ; concat with x0 = coef_a[b,0,:] ----
    if (tid < 32) {
        float e = 0.f;
        const float* wr = gru_lin_w + tid * 64;
        for (int j = 0; j < 64; ++j) e = fmaf(wr[j], s_y[j], e);
        s_v48[tid] = e;
    } else if (tid < 48) {
        s_v48[tid] = coef_a[(size_t)b * 127 * 16 + (tid - 32)];
    }
    __syncthreads();

    // ---- initial-embedding MLP: 48 -> 128 -> 128 -> 64 ----
    if (tid < 128) {
        float a = ie_b0[tid];
        const float* wr = ie_w0 + tid * 48;
        for (int j = 0; j < 48; ++j) a = fmaf(wr[j], s_v48[j], a);
        s_m1[tid] = fmaxf(a, 0.f);
    }
    __syncthreads();
    if (tid < 128) {
        float a = ie_bh[tid];
        const float* wr = ie_wh + tid * 128;
        for (int j = 0; j < 128; ++j) a = fmaf(wr[j], s_m1[j], a);
        s_m2[tid] = fmaxf(a, 0.f);
    }
    __syncthreads();
    if (tid < 64) {
        float a = ie_bout[tid];
        const float* wr = ie_wout + tid * 128;
        for (int j = 0; j < 128; ++j) a = fmaf(wr[j], s_m2[j], a);
        s_y[tid] = a;
        s_ysall[0][tid] = a;
    }
    __syncthreads();

    // ---- vector-field weights into registers ----
    // TPB=256, 1 wave/SIMD -> 512-reg unified budget/wave, 256 arch VGPRs.
    const int row2 = tid >> 1, seg2 = tid & 1;   // 2 threads per 128-row (W0/Wh)
    float w0_r[32];          // vf_w0[row2, seg2*32 .. +32]  (fp32)
    {
        const float* base = vf_w0 + row2 * 64 + seg2 * 32;
#pragma unroll
        for (int j = 0; j < 32; ++j) w0_r[j] = base[j];
    }
    unsigned int wh_r[32];   // vf_wh[row2, seg2*64 .. +64] (fp16 pairs)
    {
        const float* base = vf_wh + row2 * 128 + seg2 * 64;
#pragma unroll
        for (int j = 0; j < 32; ++j) wh_r[j] = pack2(base[2 * j], base[2 * j + 1]);
    }
    // Wout: 4 rows/thread: flat rows l*16 + cq*4 + {0..3}, l=tid>>2, cq=tid&3
    const int l_idx = tid >> 2, cq = tid & 3;
    unsigned int wq0[64], wq1[64], wq2[64], wq3[64];
    {
        const float* r0 = vf_wout + (size_t)(l_idx * 16 + cq * 4) * 128;
#pragma unroll
        for (int j = 0; j < 64; ++j) wq0[j] = pack2(r0[2 * j], r0[2 * j + 1]);
        const float* r1 = r0 + 128;
#pragma unroll
        for (int j = 0; j < 64; ++j) wq1[j] = pack2(r1[2 * j], r1[2 * j + 1]);
        const float* r2 = r0 + 256;
#pragma unroll
        for (int j = 0; j < 64; ++j) wq2[j] = pack2(r2[2 * j], r2[2 * j + 1]);
        const float* r3 = r0 + 384;
#pragma unroll
        for (int j = 0; j < 64; ++j) wq3[j] = pack2(r3[2 * j], r3[2 * j + 1]);
    }
    const float b0_r = vf_b0[row2];
    const float bh_r = vf_bh[row2];
    const int rbase = l_idx * 16 + cq * 4;
    const float bo0 = vf_bout[rbase], bo1 = vf_bout[rbase + 1];
    const float bo2 = vf_bout[rbase + 2], bo3 = vf_bout[rbase + 3];

    const size_t cofs = (size_t)b * 127 * 16;

// One RK stage: W0-combine (ACC) -> h1 ; Wh -> h2 ; Wout+contract -> k[S]
#define VF_STAGE(S, ACC, CC)                                                   \
    do {                                                                       \
        {                                                                      \
            float acc_ = (ACC);                                                \
            acc_ = dpp_add<0xB1>(acc_);  /* pair reduce (lanes 2r, 2r+1) */    \
            if (seg2 == 0) s_h1h[row2] = __float2half_rn(softplus_f(acc_ + b0_r)); \
        }                                                                      \
        __syncthreads();                                                       \
        {                                                                      \
            const __half* hb = &s_h1h[seg2 * 64];                              \
            uint4 hv_[8];                                                      \
            _Pragma("unroll")                                                  \
            for (int q = 0; q < 8; ++q)                                        \
                hv_[q] = *reinterpret_cast<const uint4*>(hb + 8 * q);          \
            float a0 = 0.f, a1 = 0.f, a2 = 0.f, a3 = 0.f;                      \
            _Pragma("unroll")                                                  \
            for (int q = 0; q < 8; ++q) {                                      \
                a0 = dot2f(wh_r[4 * q + 0], u4c(hv_[q], 0), a0);               \
                a1 = dot2f(wh_r[4 * q + 1], u4c(hv_[q], 1), a1);               \
                a2 = dot2f(wh_r[4 * q + 2], u4c(hv_[q], 2), a2);               \
                a3 = dot2f(wh_r[4 * q + 3], u4c(hv_[q], 3), a3);               \
            }                                                                  \
            float a = (a0 + a1) + (a2 + a3);                                   \
            a = dpp_add<0xB1>(a);                                              \
            if (seg2 == 0) s_h2h[row2] = __float2half_rn(softplus_f(a + bh_r)); \
        }                                                                      \
        __syncthreads();                                                       \
        {                                                                      \
            float a0 = 0.f, a1 = 0.f, a2 = 0.f, a3 = 0.f;                      \
            _Pragma("unroll")                                                  \
            for (int k4 = 0; k4 < 16; ++k4) {                                  \
                uint4 hv = *reinterpret_cast<const uint4*>(&s_h2h[8 * k4]);    \
                a0 = dot2f(wq0[4 * k4 + 0], hv.x, a0);                         \
                a1 = dot2f(wq1[4 * k4 + 0], hv.x, a1);                         \
                a2 = dot2f(wq2[4 * k4 + 0], hv.x, a2);                         \
                a3 = dot2f(wq3[4 * k4 + 0], hv.x, a3);                         \
                a0 = dot2f(wq0[4 * k4 + 1], hv.y, a0);                         \
                a1 = dot2f(wq1[4 * k4 + 1], hv.y, a1);                         \
                a2 = dot2f(wq2[4 * k4 + 1], hv.y, a2);                         \
                a3 = dot2f(wq3[4 * k4 + 1], hv.y, a3);                         \
                a0 = dot2f(wq0[4 * k4 + 2], hv.z, a0);                         \
                a1 = dot2f(wq1[4 * k4 + 2], hv.z, a1);                         \
                a2 = dot2f(wq2[4 * k4 + 2], hv.z, a2);                         \
                a3 = dot2f(wq3[4 * k4 + 2], hv.z, a3);                         \
                a0 = dot2f(wq0[4 * k4 + 3], hv.w, a0);                         \
                a1 = dot2f(wq1[4 * k4 + 3], hv.w, a1);                         \
                a2 = dot2f(wq2[4 * k4 + 3], hv.w, a2);                         \
                a3 = dot2f(wq3[4 * k4 + 3], hv.w, a3);                         \
            }                                                                  \
            float frac = fmaf((CC), hstep, f0);                                \
            float fr2 = frac * frac;                                           \
            const int c0_ = cq * 4;                                            \
            float dx0 = fmaf(3.f * s_di[c0_], fr2, fmaf(2.f * s_ci[c0_], frac, s_bi[c0_])); \
            float dx1 = fmaf(3.f * s_di[c0_ + 1], fr2, fmaf(2.f * s_ci[c0_ + 1], frac, s_bi[c0_ + 1])); \
            float dx2 = fmaf(3.f * s_di[c0_ + 2], fr2, fmaf(2.f * s_ci[c0_ + 2], frac, s_bi[c0_ + 2])); \
            float dx3 = fmaf(3.f * s_di[c0_ + 3], fr2, fmaf(2.f * s_ci[c0_ + 3], frac, s_bi[c0_ + 3])); \
            float p = tanh_f(a0 + bo0) * dx0;                                  \
            p = fmaf(tanh_f(a1 + bo1), dx1, p);                                \
            p = fmaf(tanh_f(a2 + bo2), dx2, p);                                \
            p = fmaf(tanh_f(a3 + bo3), dx3, p);                                \
            p = dpp_add<0xB1>(p);                                              \
            p = dpp_add<0x4E>(p);  /* quad sum: lanes 4l..4l+3 */              \
            if (cq == 0) s_k[(S)][l_idx] = p;                                  \
        }                                                                      \
        __syncthreads();                                                       \
    } while (0)

    // ---- main ODE loop: 127 intervals x 2 substeps x 6 stages ----
#pragma unroll 1
    for (int t = 0; t < 127; ++t) {
        // coef loads: first use (stage-0 Wout) is 2+ barriers away
        if (tid < 16) s_bi[tid] = coef_b[cofs + t * 16 + tid];
        else if (tid < 32) s_ci[tid - 16] = coef_c[cofs + t * 16 + (tid - 16)];
        else if (tid < 48) s_di[tid - 32] = coef_d[cofs + t * 16 + (tid - 32)];
        const float t0 = timestamps[t], t1 = timestamps[t + 1];
        const float hstep = (t1 - t0) * 0.5f;

#pragma unroll 1
        for (int sub = 0; sub < 2; ++sub) {
            const float f0 = (float)sub * hstep;

            float ay = dot32(w0_r, &s_y[seg2 * 32]);
            VF_STAGE(0, ay, 0.f);
            float dk0 = dot32(w0_r, &s_k[0][seg2 * 32]);
            VF_STAGE(1, fmaf(hstep * 0.2f, dk0, ay), 0.2f);
            float dk1 = dot32(w0_r, &s_k[1][seg2 * 32]);
            VF_STAGE(2, fmaf(hstep, fmaf(3.f / 40.f, dk0, (9.f / 40.f) * dk1), ay), 0.3f);
            float dk2 = dot32(w0_r, &s_k[2][seg2 * 32]);
            VF_STAGE(3, fmaf(hstep, fmaf(44.f / 45.f, dk0,
                          fmaf(-56.f / 15.f, dk1, (32.f / 9.f) * dk2)), ay), 0.8f);
            float dk3 = dot32(w0_r, &s_k[3][seg2 * 32]);
            VF_STAGE(4, fmaf(hstep, fmaf(19372.f / 6561.f, dk0,
                          fmaf(-25360.f / 2187.f, dk1,
                          fmaf(64448.f / 6561.f, dk2, (-212.f / 729.f) * dk3))), ay),
                     8.f / 9.f);
            float dk4 = dot32(w0_r, &s_k[4][seg2 * 32]);
            VF_STAGE(5, fmaf(hstep, fmaf(9017.f / 3168.f, dk0,
                          fmaf(-355.f / 33.f, dk1,
                          fmaf(46732.f / 5247.f, dk2,
                          fmaf(49.f / 176.f, dk3, (-5103.f / 18656.f) * dk4)))), ay),
                     1.f);

            // y update (Dopri5 b-weights; b[1]=0)
            if (tid < 64) {
                float yv = s_y[tid];
                yv = fmaf(hstep * (35.f / 384.f), s_k[0][tid], yv);
                yv = fmaf(hstep * (500.f / 1113.f), s_k[2][tid], yv);
                yv = fmaf(hstep * (125.f / 192.f), s_k[3][tid], yv);
                yv = fmaf(hstep * (-2187.f / 6784.f), s_k[4][tid], yv);
                yv = fmaf(hstep * (11.f / 84.f), s_k[5][tid], yv);
                s_y[tid] = yv;
                if (sub == 1) s_ysall[t + 1][tid] = yv;
            }
            __syncthreads();
        } // sub
    } // t

    // ---- decoder: per timestep 64 -> 32 -> 32 -> 8 (relu, relu, ident) ----
    const int wid = tid >> 6, lane = tid & 63;
    for (int t = wid; t < 128; t += 4) {
        const float* yy = s_ysall[t];
        float h1d = 0.f;
        if (lane < 32) {
            float a = dec_b0[lane];
            const float* wr = dec_w0 + lane * 64;
            for (int j = 0; j < 64; ++j) a = fmaf(wr[j], yy[j], a);
            h1d = fmaxf(a, 0.f);
        }
        float a2 = (lane < 32) ? dec_bh[lane] : 0.f;
#pragma unroll 8
        for (int j = 0; j < 32; ++j) {
            float hj = __shfl(h1d, j);
            if (lane < 32) a2 = fmaf(dec_wh[lane * 32 + j], hj, a2);
        }
        float h2d = fmaxf(a2, 0.f);
        float o = (lane < 8) ? dec_bout[lane] : 0.f;
#pragma unroll 8
        for (int j = 0; j < 32; ++j) {
            float hj = __shfl(h2d, j);
            if (lane < 8) o = fmaf(dec_wout[lane * 32 + j], hj, o);
        }
        if (lane < 8) out[(size_t)b * 1024 + t * 8 + lane] = o;
    }
}

extern "C" void kernel_launch(void* const* d_in, const int* in_sizes, int n_in,
                              void* d_out, int out_size, void* d_ws, size_t ws_size,
                              hipStream_t stream) {
    const float* p[29];
    for (int i = 0; i < 29; ++i) p[i] = (const float*)d_in[i];
    ncde_kernel<<<256, TPB, 0, stream>>>(
        p[0], p[1], p[2], p[3], p[4], p[5], p[6], p[7], p[8], p[9], p[10],
        p[11], p[12], p[13], p[14], p[15], p[16], p[17], p[18], p[19], p[20],
        p[21], p[22], p[23], p[24], p[25], p[26], p[27], p[28],
        (float*)d_out);
}

// Round 7
// 2288.225 us; speedup vs baseline: 1.6095x; 1.6095x over previous
//
#include <hip/hip_runtime.h>
#include <hip/hip_fp16.h>

#define TPB 512

typedef _Float16 h2v __attribute__((ext_vector_type(2)));

__device__ __forceinline__ float dot2f(unsigned int a, unsigned int b, float c) {
#if __has_builtin(__builtin_amdgcn_fdot2)
    return __builtin_amdgcn_fdot2(__builtin_bit_cast(h2v, a), __builtin_bit_cast(h2v, b), c, false);
#else
    float2 af = __half22float2(__builtin_bit_cast(__half2, a));
    float2 bf = __half22float2(__builtin_bit_cast(__half2, b));
    return fmaf(af.y, bf.y, fmaf(af.x, bf.x, c));
#endif
}

__device__ __forceinline__ unsigned int pack2(float a, float b) {
    unsigned int lo = (unsigned int)__half_as_ushort(__float2half_rn(a));
    unsigned int hi = (unsigned int)__half_as_ushort(__float2half_rn(b));
    return lo | (hi << 16);
}

__device__ __forceinline__ float softplus_f(float x) {
    return fmaxf(x, 0.f) + __logf(1.f + __expf(-fabsf(x)));
}
__device__ __forceinline__ float tanh_f(float x) {
    float e = __expf(2.f * x);
    return 1.f - 2.f / (e + 1.f);
}
__device__ __forceinline__ float sigmoid_f(float x) {
    return 1.f / (1.f + __expf(-x));
}

// DPP-based partial-wave add-reduce (no LDS, no lgkmcnt):
// 0xB1 = quad_perm(1,0,3,2) (xor1, self-inverse)
// 0x4E = quad_perm(2,3,0,1) (xor2, self-inverse)
// 0x141 = row_half_mirror (involution, direction-safe 8-lane finish)
template <int CTRL>
__device__ __forceinline__ float dpp_add(float x) {
    int m = __builtin_amdgcn_update_dpp(0, __builtin_bit_cast(int, x), CTRL, 0xF, 0xF, true);
    return x + __builtin_bit_cast(float, m);
}

__device__ __forceinline__ float dot16(const float* w, const float* base) {
    float4 a = *reinterpret_cast<const float4*>(base);
    float4 b = *reinterpret_cast<const float4*>(base + 4);
    float4 c = *reinterpret_cast<const float4*>(base + 8);
    float4 d = *reinterpret_cast<const float4*>(base + 12);
    float s0 = w[0] * a.x, s1 = w[1] * a.y, s2 = w[2] * a.z, s3 = w[3] * a.w;
    s0 = fmaf(w[4], b.x, s0);
    s1 = fmaf(w[5], b.y, s1);
    s2 = fmaf(w[6], b.z, s2);
    s3 = fmaf(w[7], b.w, s3);
    s0 = fmaf(w[8], c.x, s0);
    s1 = fmaf(w[9], c.y, s1);
    s2 = fmaf(w[10], c.z, s2);
    s3 = fmaf(w[11], c.w, s3);
    s0 = fmaf(w[12], d.x, s0);
    s1 = fmaf(w[13], d.y, s1);
    s2 = fmaf(w[14], d.z, s2);
    s3 = fmaf(w[15], d.w, s3);
    return (s0 + s1) + (s2 + s3);
}

__global__ __attribute__((amdgpu_flat_work_group_size(TPB, TPB), amdgpu_waves_per_eu(2, 2)))
void ncde_kernel(
    const float* __restrict__ timestamps, const float* __restrict__ obs,
    const float* __restrict__ coef_d, const float* __restrict__ coef_c,
    const float* __restrict__ coef_b, const float* __restrict__ coef_a,
    const float* __restrict__ gru_wih, const float* __restrict__ gru_whh,
    const float* __restrict__ gru_bih, const float* __restrict__ gru_bhh,
    const float* __restrict__ gru_lin_w,
    const float* __restrict__ ie_w0, const float* __restrict__ ie_b0,
    const float* __restrict__ ie_wh, const float* __restrict__ ie_bh,
    const float* __restrict__ ie_wout, const float* __restrict__ ie_bout,
    const float* __restrict__ vf_w0, const float* __restrict__ vf_b0,
    const float* __restrict__ vf_wh, const float* __restrict__ vf_bh,
    const float* __restrict__ vf_wout, const float* __restrict__ vf_bout,
    const float* __restrict__ dec_w0, const float* __restrict__ dec_b0,
    const float* __restrict__ dec_wh, const float* __restrict__ dec_bh,
    const float* __restrict__ dec_wout, const float* __restrict__ dec_bout,
    float* __restrict__ out)
{
    const int b = blockIdx.x;
    const int tid = threadIdx.x;

    __shared__ __align__(16) float s_ysall[128][64];   // all y states (for decoder)
    __shared__ __align__(16) float s_whh[192 * 65];    // GRU Whh, padded rows
    __shared__ __align__(16) float s_wih[192 * 9];     // GRU Wih, padded
    __shared__ __align__(16) float s_obs[24 * 8];
    __shared__ float s_gi[192];
    __shared__ float s_gh[192];
    __shared__ __align__(16) float s_y[64];            // ODE state (also GRU hidden early)
    __shared__ __align__(16) __half s_h1h[128];
    __shared__ __align__(16) __half s_h2h[128];
    __shared__ __align__(16) float s_k[6][64];
    __shared__ float s_bi[16], s_ci[16], s_di[16];
    __shared__ __align__(16) float s_v48[48];
    __shared__ float s_m1[128], s_m2[128];

    // ---- stage GRU weights into LDS ----
    for (int idx = tid; idx < 192 * 64; idx += TPB)
        s_whh[(idx >> 6) * 65 + (idx & 63)] = gru_whh[idx];
    for (int idx = tid; idx < 192 * 8; idx += TPB)
        s_wih[(idx >> 3) * 9 + (idx & 7)] = gru_wih[idx];
    if (tid < 24 * 8) s_obs[tid] = obs[(size_t)b * 192 + tid];
    const float bih_r = (tid < 192) ? gru_bih[tid] : 0.f;
    const float bhh_r = (tid < 192) ? gru_bhh[tid] : 0.f;
    if (tid < 64) s_y[tid] = 0.f;   // GRU hidden init
    __syncthreads();

    // ---- GRU over 24 steps ----
    for (int step = 0; step < 24; ++step) {
        if (tid < 192) {
            float gi = bih_r;
            const float* wr = &s_wih[tid * 9];
            const float* xr = &s_obs[step * 8];
#pragma unroll
            for (int j = 0; j < 8; ++j) gi = fmaf(wr[j], xr[j], gi);
            float g0 = bhh_r, g1 = 0.f, g2 = 0.f, g3 = 0.f;
            const float* hr = &s_whh[tid * 65];
#pragma unroll 4
            for (int j = 0; j < 64; j += 4) {
                g0 = fmaf(hr[j + 0], s_y[j + 0], g0);
                g1 = fmaf(hr[j + 1], s_y[j + 1], g1);
                g2 = fmaf(hr[j + 2], s_y[j + 2], g2);
                g3 = fmaf(hr[j + 3], s_y[j + 3], g3);
            }
            s_gi[tid] = gi;
            s_gh[tid] = (g0 + g1) + (g2 + g3);
        }
        __syncthreads();
        if (tid < 64) {
            float rg = sigmoid_f(s_gi[tid] + s_gh[tid]);
            float zg = sigmoid_f(s_gi[64 + tid] + s_gh[64 + tid]);
            float ng = tanh_f(s_gi[128 + tid] + rg * s_gh[128 + tid]);
            s_y[tid] = (1.f - zg) * ng + zg * s_y[tid];
        }
        __syncthreads();
    }

    // ---- enc = gru_lin_w @ hT ; concat with x0 = coef_a[b,0,:] ----
    if (tid < 32) {
        float e = 0.f;
        const float* wr = gru_lin_w + tid * 64;
        for (int j = 0; j < 64; ++j) e = fmaf(wr[j], s_y[j], e);
        s_v48[tid] = e;
    } else if (tid < 48) {
        s_v48[tid] = coef_a[(size_t)b * 127 * 16 + (tid - 32)];
    }
    __syncthreads();

    // ---- initial-embedding MLP: 48 -> 128 -> 128 -> 64 ----
    if (tid < 128) {
        float a = ie_b0[tid];
        const float* wr = ie_w0 + tid * 48;
        for (int j = 0; j < 48; ++j) a = fmaf(wr[j], s_v48[j], a);
        s_m1[tid] = fmaxf(a, 0.f);
    }
    __syncthreads();
    if (tid < 128) {
        float a = ie_bh[tid];
        const float* wr = ie_wh + tid * 128;
        for (int j = 0; j < 128; ++j) a = fmaf(wr[j], s_m1[j], a);
        s_m2[tid] = fmaxf(a, 0.f);
    }
    __syncthreads();
    if (tid < 64) {
        float a = ie_bout[tid];
        const float* wr = ie_wout + tid * 128;
        for (int j = 0; j < 128; ++j) a = fmaf(wr[j], s_m2[j], a);
        s_y[tid] = a;
        s_ysall[0][tid] = a;
    }
    __syncthreads();

    // ---- vector-field weights into registers (~205 total; 256/wave at 2 waves/EU) ----
    const int row4 = tid >> 2, seg4 = tid & 3;   // 4 threads per 128-row
    float w0_r[16];          // vf_w0[row4, seg4*16 .. +16]  (fp32)
    {
        const float* base = vf_w0 + row4 * 64 + seg4 * 16;
#pragma unroll
        for (int j = 0; j < 16; ++j) w0_r[j] = base[j];
    }
    unsigned int wh_r[16];   // vf_wh[row4, seg4*32 .. +32] (fp16 pairs)
    {
        const float* base = vf_wh + row4 * 128 + seg4 * 32;
#pragma unroll
        for (int j = 0; j < 16; ++j) wh_r[j] = pack2(base[2 * j], base[2 * j + 1]);
    }
    unsigned int wq0[64], wq1[64];   // vf_wout rows 2*tid, 2*tid+1 (fp16 pairs)
    {
        const float* r0 = vf_wout + (size_t)(2 * tid) * 128;
#pragma unroll
        for (int j = 0; j < 64; ++j) wq0[j] = pack2(r0[2 * j], r0[2 * j + 1]);
        const float* r1 = r0 + 128;
#pragma unroll
        for (int j = 0; j < 64; ++j) wq1[j] = pack2(r1[2 * j], r1[2 * j + 1]);
    }
    const float b0_r = vf_b0[row4];
    const float bh_r = vf_bh[row4];
    const float bo0 = vf_bout[2 * tid], bo1 = vf_bout[2 * tid + 1];
    const int l_idx = tid >> 3;       // output row l of V(64,16)
    const int c0 = 2 * (tid & 7);     // dx columns c0, c0+1

    const size_t cofs = (size_t)b * 127 * 16;

// One RK stage: W0-combine (ACC) -> h1 ; Wh -> h2 ; Wout+contract -> k[S]
#define VF_STAGE(S, ACC, CC)                                                   \
    do {                                                                       \
        {                                                                      \
            float acc_ = (ACC);                                                \
            acc_ = dpp_add<0xB1>(acc_);                                        \
            acc_ = dpp_add<0x4E>(acc_);                                        \
            if (seg4 == 0) s_h1h[row4] = __float2half_rn(softplus_f(acc_ + b0_r)); \
        }                                                                      \
        __syncthreads();                                                       \
        {                                                                      \
            const __half* hb = &s_h1h[seg4 * 32];                              \
            uint4 h0 = *reinterpret_cast<const uint4*>(hb);                    \
            uint4 h1v = *reinterpret_cast<const uint4*>(hb + 8);               \
            uint4 h2v2 = *reinterpret_cast<const uint4*>(hb + 16);             \
            uint4 h3 = *reinterpret_cast<const uint4*>(hb + 24);               \
            float a0 = dot2f(wh_r[0], h0.x, 0.f);                              \
            float a1 = dot2f(wh_r[1], h0.y, 0.f);                              \
            float a2 = dot2f(wh_r[2], h0.z, 0.f);                              \
            float a3 = dot2f(wh_r[3], h0.w, 0.f);                              \
            a0 = dot2f(wh_r[4], h1v.x, a0);                                    \
            a1 = dot2f(wh_r[5], h1v.y, a1);                                    \
            a2 = dot2f(wh_r[6], h1v.z, a2);                                    \
            a3 = dot2f(wh_r[7], h1v.w, a3);                                    \
            a0 = dot2f(wh_r[8], h2v2.x, a0);                                   \
            a1 = dot2f(wh_r[9], h2v2.y, a1);                                   \
            a2 = dot2f(wh_r[10], h2v2.z, a2);                                  \
            a3 = dot2f(wh_r[11], h2v2.w, a3);                                  \
            a0 = dot2f(wh_r[12], h3.x, a0);                                    \
            a1 = dot2f(wh_r[13], h3.y, a1);                                    \
            a2 = dot2f(wh_r[14], h3.z, a2);                                    \
            a3 = dot2f(wh_r[15], h3.w, a3);                                    \
            float a = (a0 + a1) + (a2 + a3);                                   \
            a = dpp_add<0xB1>(a);                                              \
            a = dpp_add<0x4E>(a);                                              \
            if (seg4 == 0) s_h2h[row4] = __float2half_rn(softplus_f(a + bh_r)); \
        }                                                                      \
        __syncthreads();                                                       \
        {                                                                      \
            float a0 = 0.f, a1 = 0.f, b0a = 0.f, b1a = 0.f;                    \
            _Pragma("unroll")                                                  \
            for (int k4 = 0; k4 < 16; ++k4) {                                  \
                uint4 hv = *reinterpret_cast<const uint4*>(&s_h2h[8 * k4]);    \
                a0 = dot2f(wq0[4 * k4 + 0], hv.x, a0);                         \
                b0a = dot2f(wq1[4 * k4 + 0], hv.x, b0a);                       \
                a1 = dot2f(wq0[4 * k4 + 1], hv.y, a1);                         \
                b1a = dot2f(wq1[4 * k4 + 1], hv.y, b1a);                       \
                a0 = dot2f(wq0[4 * k4 + 2], hv.z, a0);                         \
                b0a = dot2f(wq1[4 * k4 + 2], hv.z, b0a);                       \
                a1 = dot2f(wq0[4 * k4 + 3], hv.w, a1);                         \
                b1a = dot2f(wq1[4 * k4 + 3], hv.w, b1a);                       \
            }                                                                  \
            float v0 = tanh_f(a0 + a1 + bo0);                                  \
            float v1 = tanh_f(b0a + b1a + bo1);                                \
            float frac = fmaf((CC), hstep, f0);                                \
            float dx0 = fmaf(3.f * s_di[c0], frac * frac,                      \
                             fmaf(2.f * s_ci[c0], frac, s_bi[c0]));            \
            float dx1 = fmaf(3.f * s_di[c0 + 1], frac * frac,                  \
                             fmaf(2.f * s_ci[c0 + 1], frac, s_bi[c0 + 1]));    \
            float p = fmaf(v0, dx0, v1 * dx1);                                 \
            p = dpp_add<0xB1>(p);                                              \
            p = dpp_add<0x4E>(p);                                              \
            p = dpp_add<0x141>(p);  /* row_half_mirror: direction-safe 8-lane finish */ \
            if ((tid & 7) == 0) s_k[(S)][l_idx] = p;                           \
        }                                                                      \
        __syncthreads();                                                       \
    } while (0)

    // ---- main ODE loop: 127 intervals x 2 substeps x 6 stages ----
#pragma unroll 1
    for (int t = 0; t < 127; ++t) {
        // coef loads: first use (stage-0 Wout) is 2+ barriers away
        if (tid < 16) s_bi[tid] = coef_b[cofs + t * 16 + tid];
        else if (tid < 32) s_ci[tid - 16] = coef_c[cofs + t * 16 + (tid - 16)];
        else if (tid < 48) s_di[tid - 32] = coef_d[cofs + t * 16 + (tid - 32)];
        const float t0 = timestamps[t], t1 = timestamps[t + 1];
        const float hstep = (t1 - t0) * 0.5f;

#pragma unroll 1
        for (int sub = 0; sub < 2; ++sub) {
            const float f0 = (float)sub * hstep;

            float ay = dot16(w0_r, &s_y[seg4 * 16]);
            VF_STAGE(0, ay, 0.f);
            float dk0 = dot16(w0_r, &s_k[0][seg4 * 16]);
            VF_STAGE(1, fmaf(hstep * 0.2f, dk0, ay), 0.2f);
            float dk1 = dot16(w0_r, &s_k[1][seg4 * 16]);
            VF_STAGE(2, fmaf(hstep, fmaf(3.f / 40.f, dk0, (9.f / 40.f) * dk1), ay), 0.3f);
            float dk2 = dot16(w0_r, &s_k[2][seg4 * 16]);
            VF_STAGE(3, fmaf(hstep, fmaf(44.f / 45.f, dk0,
                          fmaf(-56.f / 15.f, dk1, (32.f / 9.f) * dk2)), ay), 0.8f);
            float dk3 = dot16(w0_r, &s_k[3][seg4 * 16]);
            VF_STAGE(4, fmaf(hstep, fmaf(19372.f / 6561.f, dk0,
                          fmaf(-25360.f / 2187.f, dk1,
                          fmaf(64448.f / 6561.f, dk2, (-212.f / 729.f) * dk3))), ay),
                     8.f / 9.f);
            float dk4 = dot16(w0_r, &s_k[4][seg4 * 16]);
            VF_STAGE(5, fmaf(hstep, fmaf(9017.f / 3168.f, dk0,
                          fmaf(-355.f / 33.f, dk1,
                          fmaf(46732.f / 5247.f, dk2,
                          fmaf(49.f / 176.f, dk3, (-5103.f / 18656.f) * dk4)))), ay),
                     1.f);

            // y update (Dopri5 b-weights; b[1]=0)
            if (tid < 64) {
                float yv = s_y[tid];
                yv = fmaf(hstep * (35.f / 384.f), s_k[0][tid], yv);
                yv = fmaf(hstep * (500.f / 1113.f), s_k[2][tid], yv);
                yv = fmaf(hstep * (125.f / 192.f), s_k[3][tid], yv);
                yv = fmaf(hstep * (-2187.f / 6784.f), s_k[4][tid], yv);
                yv = fmaf(hstep * (11.f / 84.f), s_k[5][tid], yv);
                s_y[tid] = yv;
                if (sub == 1) s_ysall[t + 1][tid] = yv;
            }
            __syncthreads();
        } // sub
    } // t

    // ---- decoder: per timestep 64 -> 32 -> 32 -> 8 (relu, relu, ident) ----
    const int wid = tid >> 6, lane = tid & 63;
    for (int t = wid; t < 128; t += 8) {
        const float* yy = s_ysall[t];
        float h1d = 0.f;
        if (lane < 32) {
            float a = dec_b0[lane];
            const float* wr = dec_w0 + lane * 64;
            for (int j = 0; j < 64; ++j) a = fmaf(wr[j], yy[j], a);
            h1d = fmaxf(a, 0.f);
        }
        float a2 = (lane < 32) ? dec_bh[lane] : 0.f;
#pragma unroll 8
        for (int j = 0; j < 32; ++j) {
            float hj = __shfl(h1d, j);
            if (lane < 32) a2 = fmaf(dec_wh[lane * 32 + j], hj, a2);
        }
        float h2d = fmaxf(a2, 0.f);
        float o = (lane < 8) ? dec_bout[lane] : 0.f;
#pragma unroll 8
        for (int j = 0; j < 32; ++j) {
            float hj = __shfl(h2d, j);
            if (lane < 8) o = fmaf(dec_wout[lane * 32 + j], hj, o);
        }
        if (lane < 8) out[(size_t)b * 1024 + t * 8 + lane] = o;
    }
}

extern "C" void kernel_launch(void* const* d_in, const int* in_sizes, int n_in,
                              void* d_out, int out_size, void* d_ws, size_t ws_size,
                              hipStream_t stream) {
    const float* p[29];
    for (int i = 0; i < 29; ++i) p[i] = (const float*)d_in[i];
    ncde_kernel<<<256, TPB, 0, stream>>>(
        p[0], p[1], p[2], p[3], p[4], p[5], p[6], p[7], p[8], p[9], p[10],
        p[11], p[12], p[13], p[14], p[15], p[16], p[17], p[18], p[19], p[20],
        p[21], p[22], p[23], p[24], p[25], p[26], p[27], p[28],
        (float*)d_out);
}